// Round 4
// baseline (1478.477 us; speedup 1.0000x reference)
//
#include <hip/hip_runtime.h>
#include <math.h>

typedef __attribute__((ext_vector_type(8))) short short8;
typedef __attribute__((ext_vector_type(4))) float floatx4;

#define TOKENS 50176   // 16 * 64 windows * 49

__device__ __forceinline__ unsigned short f2bf(float f) {
  union { float f; unsigned int i; } x; x.f = f;
  unsigned int r = x.i + 0x7fffu + ((x.i >> 16) & 1u);
  return (unsigned short)(r >> 16);
}
__device__ __forceinline__ float bf2f(unsigned short u) {
  union { unsigned int i; float f; } x; x.i = ((unsigned int)u) << 16; return x.f;
}

// -------------------------------------------------------------------------
// Per-token LN statistics over fp32 rows: one wave per token -> (mu, rstd).
// -------------------------------------------------------------------------
__global__ __launch_bounds__(256) void ln_stats_kernel(
    const float* __restrict__ xin, float2* __restrict__ stats) {
  int gw = (blockIdx.x * 256 + threadIdx.x) >> 6;
  int lane = threadIdx.x & 63;
  if (gw >= TOKENS) return;
  const float* rp = xin + (size_t)gw * 512 + lane * 8;
  floatx4 a = *(const floatx4*)rp;
  floatx4 b = *(const floatx4*)(rp + 4);
  float s = 0.f, ss = 0.f;
#pragma unroll
  for (int k = 0; k < 4; ++k) { s += a[k]; ss += a[k] * a[k]; }
#pragma unroll
  for (int k = 0; k < 4; ++k) { s += b[k]; ss += b[k] * b[k]; }
  for (int m = 32; m >= 1; m >>= 1) {
    s  += __shfl_xor(s, m, 64);
    ss += __shfl_xor(ss, m, 64);
  }
  float mu = s * (1.f / 512.f);
  float var = ss * (1.f / 512.f) - mu * mu;
  float rstd = rsqrtf(var + 1e-5f);
  if (lane == 0) stats[gw] = make_float2(mu, rstd);
}

// -------------------------------------------------------------------------
// GEMM: out[m,n] = sum_k Asrc[m,k] * Bw[n,k] + bias[n]
// Bw, bias: fp32 (converted to bf16 at staging). Internal MFMA bf16.
// 128x128 tile, BK=64, 4 waves (2x2 of 64x64), 16x16x32 bf16 MFMA.
// ASRC 0: A = bf16 internal buffer, local rows       (proj in, fc2 in)
// ASRC 1: A = fp32 x1, roll(-3)+window gather + fused LN1, K=512
// ASRC 2: A = fp32 x (d_out), rows mofs+m + fused LN2, K=512
// EPI  0: +bias -> bf16 out[m*N+n]
// EPI  1: +bias, scatter rows via reverse/roll, +res -> fp32 out (orig layout)
// EPI  2: +bias, exact GELU -> bf16 out[m*N+n]
// EPI  3: +bias, +res[m*512+n] -> fp32 out[m*512+n] (in place)
// -------------------------------------------------------------------------
template <int ASRC, int EPI>
__global__ __launch_bounds__(256, 2) void gemm_k(
    const void* __restrict__ Asrc,
    const float* __restrict__ Bw,
    const float* __restrict__ bias,
    void* __restrict__ outp,
    const float* __restrict__ res,
    const float2* __restrict__ stats,
    const float* __restrict__ lng,
    const float* __restrict__ lnb,
    int mofs, int Mrows, int N, int K) {
  constexpr int LDK = 72;  // 64 + 8 halfword pad
  __shared__ short lA[128 * LDK];
  __shared__ short lB[128 * LDK];

  int tid = threadIdx.x;
  int lr = tid >> 3;            // 0..31
  int lc = (tid & 7) * 8;       // 0..56 step 8

  const short* rowA16[4];
  const float* rowA32[4];
  float mu[4], rs[4];
#pragma unroll
  for (int it = 0; it < 4; ++it) {
    int mr = blockIdx.x * 128 + lr + it * 32;
    if (mr >= Mrows) mr = Mrows - 1;      // clamp (dup row; epilogue guards)
    if (ASRC == 0) {
      rowA16[it] = (const short*)Asrc + (size_t)mr * K;
    } else if (ASRC == 1) {
      int mg = mofs + mr;
      int nn = mg % 49, wI = mg / 49;
      int i = nn / 7, j = nn % 7;
      int wwI = wI & 7, whI = (wI >> 3) & 7, bb = wI >> 6;
      int hs = (whI * 7 + i + 3) % 56;
      int wsS = (wwI * 7 + j + 3) % 56;
      size_t src = (size_t)bb * 3136 + (size_t)hs * 56 + wsS;
      rowA32[it] = (const float*)Asrc + src * 512;
      float2 st = stats[src];
      mu[it] = st.x; rs[it] = st.y;
    } else {
      int mg = mofs + mr;
      rowA32[it] = (const float*)Asrc + (size_t)mg * 512;
      float2 st = stats[mg];
      mu[it] = st.x; rs[it] = st.y;
    }
  }
  const float* Bg = Bw + (size_t)(blockIdx.y * 128 + lr) * K + lc;

  int wave = tid >> 6, lane = tid & 63;
  int wm = (wave >> 1) * 64;
  int wn = (wave & 1) * 64;
  int l15 = lane & 15;
  int kq = (lane >> 4) * 8;

  short8 ar16[4];
  floatx4 ar32[4][2];
  floatx4 br[4][2];
#pragma unroll
  for (int it = 0; it < 4; ++it) {
    if (ASRC == 0) {
      ar16[it] = *(const short8*)(rowA16[it] + lc);
    } else {
      ar32[it][0] = *(const floatx4*)(rowA32[it] + lc);
      ar32[it][1] = *(const floatx4*)(rowA32[it] + lc + 4);
    }
    br[it][0] = *(const floatx4*)(Bg + (size_t)it * 32 * K);
    br[it][1] = *(const floatx4*)(Bg + (size_t)it * 32 * K + 4);
  }
  floatx4 acc[4][4] = {};

  int KT = K / 64;
  for (int kt = 0; kt < KT; ++kt) {
    // ---- stage A ----
    if (ASRC == 0) {
#pragma unroll
      for (int it = 0; it < 4; ++it)
        *(short8*)&lA[(lr + it * 32) * LDK + lc] = ar16[it];
    } else {
      const float* gp = lng + kt * 64 + lc;
      const float* bp = lnb + kt * 64 + lc;
      floatx4 g0 = *(const floatx4*)gp, g1 = *(const floatx4*)(gp + 4);
      floatx4 b0 = *(const floatx4*)bp, b1 = *(const floatx4*)(bp + 4);
#pragma unroll
      for (int it = 0; it < 4; ++it) {
        short8 o8;
#pragma unroll
        for (int k = 0; k < 4; ++k) {
          float v0 = (ar32[it][0][k] - mu[it]) * rs[it] * g0[k] + b0[k];
          float v1 = (ar32[it][1][k] - mu[it]) * rs[it] * g1[k] + b1[k];
          o8[k]     = (short)f2bf(v0);
          o8[k + 4] = (short)f2bf(v1);
        }
        *(short8*)&lA[(lr + it * 32) * LDK + lc] = o8;
      }
    }
    // ---- stage B (fp32 -> bf16) ----
#pragma unroll
    for (int it = 0; it < 4; ++it) {
      short8 o8;
#pragma unroll
      for (int k = 0; k < 4; ++k) {
        o8[k]     = (short)f2bf(br[it][0][k]);
        o8[k + 4] = (short)f2bf(br[it][1][k]);
      }
      *(short8*)&lB[(lr + it * 32) * LDK + lc] = o8;
    }
    __syncthreads();
    // ---- prefetch next K-tile ----
    if (kt + 1 < KT) {
      int ko = (kt + 1) * 64;
#pragma unroll
      for (int it = 0; it < 4; ++it) {
        if (ASRC == 0) {
          ar16[it] = *(const short8*)(rowA16[it] + ko + lc);
        } else {
          ar32[it][0] = *(const floatx4*)(rowA32[it] + ko + lc);
          ar32[it][1] = *(const floatx4*)(rowA32[it] + ko + lc + 4);
        }
        br[it][0] = *(const floatx4*)(Bg + ko + (size_t)it * 32 * K);
        br[it][1] = *(const floatx4*)(Bg + ko + (size_t)it * 32 * K + 4);
      }
    }
    // ---- MFMA ----
#pragma unroll
    for (int ks = 0; ks < 2; ++ks) {
      short8 af[4], bfr[4];
#pragma unroll
      for (int tm = 0; tm < 4; ++tm)
        af[tm] = *(short8*)&lA[(wm + tm * 16 + l15) * LDK + ks * 32 + kq];
#pragma unroll
      for (int tn = 0; tn < 4; ++tn)
        bfr[tn] = *(short8*)&lB[(wn + tn * 16 + l15) * LDK + ks * 32 + kq];
#pragma unroll
      for (int tm = 0; tm < 4; ++tm)
#pragma unroll
        for (int tn = 0; tn < 4; ++tn)
          acc[tm][tn] = __builtin_amdgcn_mfma_f32_16x16x32_bf16(af[tm], bfr[tn], acc[tm][tn], 0, 0, 0);
    }
    __syncthreads();
  }

  // epilogue: D row = (lane>>4)*4+reg, D col = lane&15
  int colb = blockIdx.y * 128 + wn + l15;
  int rowb = blockIdx.x * 128 + wm + ((lane >> 4) << 2);
#pragma unroll
  for (int tm = 0; tm < 4; ++tm) {
#pragma unroll
    for (int rg = 0; rg < 4; ++rg) {
      int m = rowb + tm * 16 + rg;
      if (m >= Mrows) continue;
      size_t outrow;
      const float* resrow = nullptr;
      if (EPI == 1) {
        int mg = mofs + m;
        int nn = mg % 49, wI = mg / 49;
        int i = nn / 7, j = nn % 7;
        int wwI = wI & 7, whI = (wI >> 3) & 7, bb = wI >> 6;
        int hs = (whI * 7 + i + 3) % 56;
        int wsS = (wwI * 7 + j + 3) % 56;
        size_t orig = (size_t)bb * 3136 + (size_t)hs * 56 + wsS;
        outrow = orig * 512;
        resrow = res + orig * 512;
      } else {
        outrow = (size_t)m * N;
        if (EPI == 3) resrow = res + (size_t)m * 512;
      }
#pragma unroll
      for (int tn = 0; tn < 4; ++tn) {
        int n = colb + tn * 16;
        float v = acc[tm][tn][rg] + bias[n];
        if (EPI == 2) v = 0.5f * v * (1.f + erff(v * 0.70710678118654752f));
        if (EPI == 0 || EPI == 2) {
          ((unsigned short*)outp)[outrow + n] = f2bf(v);
        } else {
          ((float*)outp)[outrow + n] = v + resrow[n];
        }
      }
    }
  }
}

// -------------------------------------------------------------------------
// Windowed attention, x1 branch only (x2 branch dead in reference:
// xw[:,:,:C] selects heads 0..15 = attn1@v1; softmax is per-head-row).
// One block per window; 4 waves; each wave does 4 heads sequentially.
// Lane r (<49) owns query row r. k/v staged to per-wave LDS as fp32.
// -------------------------------------------------------------------------
__global__ __launch_bounds__(256) void attn_kernel(
    const unsigned short* __restrict__ qkv,   // (CHW*49, 1536) bf16 internal
    const float* __restrict__ rel_tab,        // (169,16) fp32
    unsigned short* __restrict__ obuf,        // (CHW*49, 512) bf16 internal
    int wofs) {
  __shared__ float ldsK[4][49 * 32];
  __shared__ float ldsV[4][49 * 32];
  int wl = blockIdx.x;
  int wg = wofs + wl;
  int wave = threadIdx.x >> 6, lane = threadIdx.x & 63;
  int wh = (wg >> 3) & 7, ww = wg & 7;
  int r = lane;
  int ir = r / 7, jr = r % 7;
  int rh = (wh < 7) ? 0 : ((ir < 4) ? 1 : 2);
  int rw = (ww < 7) ? 0 : ((jr < 4) ? 1 : 2);
  int labr = rh * 3 + rw;
  const size_t base = (size_t)wl * 49 * 1536;

  for (int hh = 0; hh < 4; ++hh) {
    int head = wave * 4 + hh;
    __syncthreads();
    for (int idx = lane; idx < 49 * 32; idx += 64) {
      int rr = idx >> 5, d = idx & 31;
      size_t ro = base + (size_t)rr * 1536 + head * 32 + d;
      ldsK[wave][idx] = bf2f(qkv[ro + 512]);
      ldsV[wave][idx] = bf2f(qkv[ro + 1024]);
    }
    __syncthreads();
    if (r < 49) {
      float qf[32];
#pragma unroll
      for (int d8 = 0; d8 < 4; ++d8) {
        short8 raw = *(const short8*)(qkv + base + (size_t)r * 1536 + head * 32 + d8 * 8);
#pragma unroll
        for (int k = 0; k < 8; ++k) qf[d8 * 8 + k] = bf2f((unsigned short)raw[k]);
      }
      float sarr[49];
      float mx = -1e30f;
#pragma unroll
      for (int c = 0; c < 49; ++c) {
        float dot = 0.f;
#pragma unroll
        for (int d = 0; d < 32; ++d) dot += qf[d] * ldsK[wave][c * 32 + d];
        int ic = c / 7, jc = c % 7;
        int ch = (wh < 7) ? 0 : ((ic < 4) ? 1 : 2);
        int cw = (ww < 7) ? 0 : ((jc < 4) ? 1 : 2);
        float mask = ((ch * 3 + cw) != labr) ? -100.f : 0.f;
        int ridx = (ir - ic + 6) * 13 + (jr - jc + 6);
        float bv = rel_tab[ridx * 16 + head];
        float sv = dot * 0.17677669529663687f + bv + mask;
        sarr[c] = sv;
        mx = fmaxf(mx, sv);
      }
      float sum = 0.f;
#pragma unroll
      for (int c = 0; c < 49; ++c) { float e = __expf(sarr[c] - mx); sarr[c] = e; sum += e; }
      float inv = 1.f / sum;
      float o[32];
#pragma unroll
      for (int d = 0; d < 32; ++d) o[d] = 0.f;
#pragma unroll
      for (int c = 0; c < 49; ++c) {
        float p = sarr[c];
#pragma unroll
        for (int d = 0; d < 32; ++d) o[d] += p * ldsV[wave][c * 32 + d];
      }
      unsigned short* dst = obuf + (size_t)(wl * 49 + r) * 512 + head * 32;
#pragma unroll
      for (int d8 = 0; d8 < 4; ++d8) {
        short8 pk;
#pragma unroll
        for (int k = 0; k < 8; ++k) pk[k] = (short)f2bf(o[d8 * 8 + k] * inv);
        *(short8*)(dst + d8 * 8) = pk;
      }
    }
  }
}

// -------------------------------------------------------------------------
extern "C" void kernel_launch(void* const* d_in, const int* in_sizes, int n_in,
                              void* d_out, int out_size, void* d_ws, size_t ws_size,
                              hipStream_t stream) {
  const float* x1     = (const float*)d_in[0];
  // d_in[1] = x2 : dead code in reference (xw[:,:,:C] uses only the x1 branch)
  const float* n1g    = (const float*)d_in[2];
  const float* n1b    = (const float*)d_in[3];
  const float* qkv_w  = (const float*)d_in[4];
  const float* qkv_b  = (const float*)d_in[5];
  const float* rel_t  = (const float*)d_in[6];
  const float* proj_w = (const float*)d_in[7];
  const float* proj_b = (const float*)d_in[8];
  const float* n2g    = (const float*)d_in[9];
  const float* n2b    = (const float*)d_in[10];
  const float* fc1_w  = (const float*)d_in[11];
  const float* fc1_b  = (const float*)d_in[12];
  const float* fc2_w  = (const float*)d_in[13];
  const float* fc2_b  = (const float*)d_in[14];
  float* outp = (float*)d_out;   // fp32; also holds x (residual-1 result)

  // ---- workspace: stats (401,408 B) + CH*4096 B of bf16 chunk buffers ----
  const size_t statB = (size_t)TOKENS * sizeof(float2);
  const int wpcs[11] = {1024, 512, 256, 128, 64, 32, 16, 8, 4, 2, 1};
  int CH = 49;  // last-resort fallback
  for (int i = 0; i < 11; ++i) {
    int cht = 49 * wpcs[i];
    size_t need = statB + (size_t)cht * 4096;
    if (need <= ws_size) { CH = cht; break; }
  }
  const int NC = TOKENS / CH;
  char* ws = (char*)d_ws;
  float2* stats = (float2*)ws;
  unsigned short* bufQ = (unsigned short*)(ws + statB);   // CH x 1536 bf16
  unsigned short* bufO = bufQ + (size_t)CH * 1536;        // CH x 512  bf16
  unsigned short* bufH = bufQ;                            // CH x 2048 bf16 (reuse)

  // LN1 stats over x1 (original token order)
  ln_stats_kernel<<<TOKENS / 4, 256, 0, stream>>>(x1, stats);

  // phase A: qkv (fused gather+LN1) -> attention -> proj(+scatter + x1 residual)
  for (int c = 0; c < NC; ++c) {
    int mofs = c * CH;
    int tiles = (CH + 127) / 128;
    gemm_k<1, 0><<<dim3(tiles, 12), 256, 0, stream>>>(
        x1, qkv_w, qkv_b, bufQ, nullptr, stats, n1g, n1b, mofs, CH, 1536, 512);
    attn_kernel<<<CH / 49, 256, 0, stream>>>(bufQ, rel_t, bufO, mofs / 49);
    gemm_k<0, 1><<<dim3(tiles, 4), 256, 0, stream>>>(
        bufO, proj_w, proj_b, outp, x1, nullptr, nullptr, nullptr, mofs, CH, 512, 512);
  }

  // LN2 stats over x (= d_out, fp32)
  ln_stats_kernel<<<TOKENS / 4, 256, 0, stream>>>(outp, stats);

  // phase B: fc1 (fused LN2, GELU) -> fc2 (+x residual, in place)
  for (int c = 0; c < NC; ++c) {
    int mofs = c * CH;
    int tiles = (CH + 127) / 128;
    gemm_k<2, 2><<<dim3(tiles, 16), 256, 0, stream>>>(
        outp, fc1_w, fc1_b, bufH, nullptr, stats, n2g, n2b, mofs, CH, 2048, 512);
    float* oc = outp + (size_t)mofs * 512;
    gemm_k<0, 3><<<dim3(tiles, 4), 256, 0, stream>>>(
        bufH, fc2_w, fc2_b, oc, oc, nullptr, nullptr, nullptr, 0, CH, 512, 2048);
  }
}

// Round 5
// 1387.683 us; speedup vs baseline: 1.0654x; 1.0654x over previous
//
#include <hip/hip_runtime.h>
#include <math.h>

typedef __attribute__((ext_vector_type(8))) short short8;
typedef __attribute__((ext_vector_type(4))) float floatx4;

#define TOKENS 50176   // 16 * 64 windows * 49

__device__ __forceinline__ unsigned short f2bf(float f) {
  union { float f; unsigned int i; } x; x.f = f;
  unsigned int r = x.i + 0x7fffu + ((x.i >> 16) & 1u);
  return (unsigned short)(r >> 16);
}
__device__ __forceinline__ float bf2f(unsigned short u) {
  union { unsigned int i; float f; } x; x.i = ((unsigned int)u) << 16; return x.f;
}

// -------------------------------------------------------------------------
// LN1 + roll(-3,-3) + window-partition gather, fp32 -> bf16.
// One wave per destination (windowed) token.
// -------------------------------------------------------------------------
__global__ __launch_bounds__(256) void prep_ln1(
    const float* __restrict__ x1, const float* __restrict__ g,
    const float* __restrict__ b, unsigned short* __restrict__ a1w) {
  int gw = (blockIdx.x * 256 + threadIdx.x) >> 6;
  int lane = threadIdx.x & 63;
  if (gw >= TOKENS) return;
  int n = gw % 49, w = gw / 49;
  int i = n / 7, j = n % 7;
  int ww = w & 7, wh = (w >> 3) & 7, bb = w >> 6;
  int hs = (wh * 7 + i + 3) % 56;
  int wsS = (ww * 7 + j + 3) % 56;
  const float* rp = x1 + ((size_t)bb * 3136 + (size_t)hs * 56 + wsS) * 512 + lane * 8;
  floatx4 a0 = *(const floatx4*)rp;
  floatx4 a1 = *(const floatx4*)(rp + 4);
  float s = 0.f, ss = 0.f;
#pragma unroll
  for (int k = 0; k < 4; ++k) { s += a0[k]; ss += a0[k] * a0[k]; }
#pragma unroll
  for (int k = 0; k < 4; ++k) { s += a1[k]; ss += a1[k] * a1[k]; }
  for (int m = 32; m >= 1; m >>= 1) {
    s  += __shfl_xor(s, m, 64);
    ss += __shfl_xor(ss, m, 64);
  }
  float mu = s * (1.f / 512.f);
  float var = ss * (1.f / 512.f) - mu * mu;
  float rstd = rsqrtf(var + 1e-5f);
  floatx4 g0 = *(const floatx4*)(g + lane * 8);
  floatx4 g1 = *(const floatx4*)(g + lane * 8 + 4);
  floatx4 b0 = *(const floatx4*)(b + lane * 8);
  floatx4 b1 = *(const floatx4*)(b + lane * 8 + 4);
  short8 o8;
#pragma unroll
  for (int k = 0; k < 4; ++k) {
    o8[k]     = (short)f2bf((a0[k] - mu) * rstd * g0[k] + b0[k]);
    o8[k + 4] = (short)f2bf((a1[k] - mu) * rstd * g1[k] + b1[k]);
  }
  *(short8*)(a1w + (size_t)gw * 512 + lane * 8) = o8;
}

// -------------------------------------------------------------------------
// Per-token LN statistics over fp32 rows -> (mu, rstd). (for LN2)
// -------------------------------------------------------------------------
__global__ __launch_bounds__(256) void ln_stats_kernel(
    const float* __restrict__ xin, float2* __restrict__ stats) {
  int gw = (blockIdx.x * 256 + threadIdx.x) >> 6;
  int lane = threadIdx.x & 63;
  if (gw >= TOKENS) return;
  const float* rp = xin + (size_t)gw * 512 + lane * 8;
  floatx4 a = *(const floatx4*)rp;
  floatx4 b = *(const floatx4*)(rp + 4);
  float s = 0.f, ss = 0.f;
#pragma unroll
  for (int k = 0; k < 4; ++k) { s += a[k]; ss += a[k] * a[k]; }
#pragma unroll
  for (int k = 0; k < 4; ++k) { s += b[k]; ss += b[k] * b[k]; }
  for (int m = 32; m >= 1; m >>= 1) {
    s  += __shfl_xor(s, m, 64);
    ss += __shfl_xor(ss, m, 64);
  }
  float mu = s * (1.f / 512.f);
  float var = ss * (1.f / 512.f) - mu * mu;
  float rstd = rsqrtf(var + 1e-5f);
  if (lane == 0) stats[gw] = make_float2(mu, rstd);
}

// -------------------------------------------------------------------------
// Column-looping GEMM: out[m,n] = sum_k A[m,k]*Bw[n,k] + bias[n]
// Block owns 128 rows; loops over CB col-tiles (A-tile stays hot in L2/L3).
// by = blockIdx.y*CB+cb. 128x128 tile, BK=64, 4 waves, 16x16x32 bf16 MFMA.
// ASRC 0: A = bf16 buffer, row stride lda
// ASRC 2: A = fp32 buffer + fused LN (stats/lng/lnb), row stride lda
// EPI 0: +bias -> bf16 out[m*N+n]
// EPI 1: +bias, reverse/roll row scatter, +res -> fp32 out (orig layout)
// EPI 2: +bias, exact GELU -> bf16 out[m*N+n]
// EPI 3: +bias, +res[m*512+n] -> fp32 out[m*512+n] (in place)
// -------------------------------------------------------------------------
template <int ASRC, int EPI>
__global__ __launch_bounds__(256, 2) void gemm_col(
    const void* __restrict__ Asrc,
    const float* __restrict__ Bw,
    const float* __restrict__ bias,
    void* __restrict__ outp,
    const float* __restrict__ res,
    const float2* __restrict__ stats,
    const float* __restrict__ lng,
    const float* __restrict__ lnb,
    int N, int K, int lda, int CB) {
  constexpr int LDK = 72;  // 64 + 8 halfword pad
  __shared__ short lA[128 * LDK];
  __shared__ short lB[128 * LDK];

  int tid = threadIdx.x;
  int lr = tid >> 3;            // 0..31
  int lc = (tid & 7) * 8;       // 0..56 step 8

  const short* rowA16[4];
  const float* rowA32[4];
  float mu[4], rs[4];
#pragma unroll
  for (int it = 0; it < 4; ++it) {
    int mr = blockIdx.x * 128 + lr + it * 32;
    if (ASRC == 0) {
      rowA16[it] = (const short*)Asrc + (size_t)mr * lda;
    } else {
      rowA32[it] = (const float*)Asrc + (size_t)mr * lda;
      float2 st = stats[mr];
      mu[it] = st.x; rs[it] = st.y;
    }
  }

  int wave = tid >> 6, lane = tid & 63;
  int wm = (wave >> 1) * 64;
  int wn = (wave & 1) * 64;
  int l15 = lane & 15;
  int kq = (lane >> 4) * 8;
  int KT = K / 64;

  for (int cb = 0; cb < CB; ++cb) {
    int by = blockIdx.y * CB + cb;
    const float* Bg = Bw + (size_t)(by * 128 + lr) * K + lc;

    short8 ar16[4];
    floatx4 ar32[4][2];
    floatx4 br[4][2];
#pragma unroll
    for (int it = 0; it < 4; ++it) {
      if (ASRC == 0) {
        ar16[it] = *(const short8*)(rowA16[it] + lc);
      } else {
        ar32[it][0] = *(const floatx4*)(rowA32[it] + lc);
        ar32[it][1] = *(const floatx4*)(rowA32[it] + lc + 4);
      }
      br[it][0] = *(const floatx4*)(Bg + (size_t)it * 32 * K);
      br[it][1] = *(const floatx4*)(Bg + (size_t)it * 32 * K + 4);
    }
    floatx4 acc[4][4] = {};

    for (int kt = 0; kt < KT; ++kt) {
      // ---- stage A ----
      if (ASRC == 0) {
#pragma unroll
        for (int it = 0; it < 4; ++it)
          *(short8*)&lA[(lr + it * 32) * LDK + lc] = ar16[it];
      } else {
        const float* gp = lng + kt * 64 + lc;
        const float* bp = lnb + kt * 64 + lc;
        floatx4 g0 = *(const floatx4*)gp, g1 = *(const floatx4*)(gp + 4);
        floatx4 b0 = *(const floatx4*)bp, b1 = *(const floatx4*)(bp + 4);
#pragma unroll
        for (int it = 0; it < 4; ++it) {
          short8 o8;
#pragma unroll
          for (int k = 0; k < 4; ++k) {
            o8[k]     = (short)f2bf((ar32[it][0][k] - mu[it]) * rs[it] * g0[k] + b0[k]);
            o8[k + 4] = (short)f2bf((ar32[it][1][k] - mu[it]) * rs[it] * g1[k] + b1[k]);
          }
          *(short8*)&lA[(lr + it * 32) * LDK + lc] = o8;
        }
      }
      // ---- stage B (fp32 -> bf16) ----
#pragma unroll
      for (int it = 0; it < 4; ++it) {
        short8 o8;
#pragma unroll
        for (int k = 0; k < 4; ++k) {
          o8[k]     = (short)f2bf(br[it][0][k]);
          o8[k + 4] = (short)f2bf(br[it][1][k]);
        }
        *(short8*)&lB[(lr + it * 32) * LDK + lc] = o8;
      }
      __syncthreads();
      // ---- prefetch next K-tile ----
      if (kt + 1 < KT) {
        int ko = (kt + 1) * 64;
#pragma unroll
        for (int it = 0; it < 4; ++it) {
          if (ASRC == 0) {
            ar16[it] = *(const short8*)(rowA16[it] + ko + lc);
          } else {
            ar32[it][0] = *(const floatx4*)(rowA32[it] + ko + lc);
            ar32[it][1] = *(const floatx4*)(rowA32[it] + ko + lc + 4);
          }
          br[it][0] = *(const floatx4*)(Bg + ko + (size_t)it * 32 * K);
          br[it][1] = *(const floatx4*)(Bg + ko + (size_t)it * 32 * K + 4);
        }
      }
      // ---- MFMA ----
#pragma unroll
      for (int ks = 0; ks < 2; ++ks) {
        short8 af[4], bfr[4];
#pragma unroll
        for (int tm = 0; tm < 4; ++tm)
          af[tm] = *(short8*)&lA[(wm + tm * 16 + l15) * LDK + ks * 32 + kq];
#pragma unroll
        for (int tn = 0; tn < 4; ++tn)
          bfr[tn] = *(short8*)&lB[(wn + tn * 16 + l15) * LDK + ks * 32 + kq];
#pragma unroll
        for (int tm = 0; tm < 4; ++tm)
#pragma unroll
          for (int tn = 0; tn < 4; ++tn)
            acc[tm][tn] = __builtin_amdgcn_mfma_f32_16x16x32_bf16(af[tm], bfr[tn], acc[tm][tn], 0, 0, 0);
      }
      __syncthreads();
    }

    // ---- epilogue (D row = (lane>>4)*4+reg, D col = lane&15) ----
    int colb = by * 128 + wn + l15;
    int rowb = blockIdx.x * 128 + wm + ((lane >> 4) << 2);
#pragma unroll
    for (int tm = 0; tm < 4; ++tm) {
#pragma unroll
      for (int rg = 0; rg < 4; ++rg) {
        int m = rowb + tm * 16 + rg;
        size_t outrow;
        const float* resrow = nullptr;
        if (EPI == 1) {
          int nn = m % 49, wI = m / 49;
          int i = nn / 7, j = nn % 7;
          int wwI = wI & 7, whI = (wI >> 3) & 7, bb = wI >> 6;
          int hs = (whI * 7 + i + 3) % 56;
          int wsS = (wwI * 7 + j + 3) % 56;
          size_t orig = (size_t)bb * 3136 + (size_t)hs * 56 + wsS;
          outrow = orig * 512;
          resrow = res + orig * 512;
        } else {
          outrow = (size_t)m * N;
          if (EPI == 3) resrow = res + (size_t)m * 512;
        }
#pragma unroll
        for (int tn = 0; tn < 4; ++tn) {
          int n = colb + tn * 16;
          float v = acc[tm][tn][rg] + bias[n];
          if (EPI == 2) v = 0.5f * v * (1.f + erff(v * 0.70710678118654752f));
          if (EPI == 0 || EPI == 2) {
            ((unsigned short*)outp)[outrow + n] = f2bf(v);
          } else {
            ((float*)outp)[outrow + n] = v + resrow[n];
          }
        }
      }
    }
  }
}

// -------------------------------------------------------------------------
// Windowed attention, x1 branch only (x2 branch dead in reference:
// xw[:,:,:C] selects heads 0..15 = attn1@v1; softmax is per-head-row).
// One block per window; 4 waves x 4 heads each. O written IN PLACE into the
// Q columns of the qkv buffer (each head's Q is dead once consumed).
// -------------------------------------------------------------------------
__global__ __launch_bounds__(256) void attn_kernel(
    unsigned short* qkv,                      // (1024*49, 1536) bf16, in/out
    const float* __restrict__ rel_tab) {      // (169,16) fp32
  __shared__ float ldsK[4][49 * 32];
  __shared__ float ldsV[4][49 * 32];
  int wg = blockIdx.x;
  int wave = threadIdx.x >> 6, lane = threadIdx.x & 63;
  int wh = (wg >> 3) & 7, ww = wg & 7;
  int r = lane;
  int ir = r / 7, jr = r % 7;
  int rh = (wh < 7) ? 0 : ((ir < 4) ? 1 : 2);
  int rw = (ww < 7) ? 0 : ((jr < 4) ? 1 : 2);
  int labr = rh * 3 + rw;
  const size_t base = (size_t)wg * 49 * 1536;

  for (int hh = 0; hh < 4; ++hh) {
    int head = wave * 4 + hh;
    __syncthreads();
    for (int idx = lane; idx < 49 * 32; idx += 64) {
      int rr = idx >> 5, d = idx & 31;
      size_t ro = base + (size_t)rr * 1536 + head * 32 + d;
      ldsK[wave][idx] = bf2f(qkv[ro + 512]);
      ldsV[wave][idx] = bf2f(qkv[ro + 1024]);
    }
    __syncthreads();
    if (r < 49) {
      float qf[32];
#pragma unroll
      for (int d8 = 0; d8 < 4; ++d8) {
        short8 raw = *(const short8*)(qkv + base + (size_t)r * 1536 + head * 32 + d8 * 8);
#pragma unroll
        for (int k = 0; k < 8; ++k) qf[d8 * 8 + k] = bf2f((unsigned short)raw[k]);
      }
      float sarr[49];
      float mx = -1e30f;
#pragma unroll
      for (int c = 0; c < 49; ++c) {
        float dot = 0.f;
#pragma unroll
        for (int d = 0; d < 32; ++d) dot += qf[d] * ldsK[wave][c * 32 + d];
        int ic = c / 7, jc = c % 7;
        int ch = (wh < 7) ? 0 : ((ic < 4) ? 1 : 2);
        int cw = (ww < 7) ? 0 : ((jc < 4) ? 1 : 2);
        float mask = ((ch * 3 + cw) != labr) ? -100.f : 0.f;
        int ridx = (ir - ic + 6) * 13 + (jr - jc + 6);
        float sv = dot * 0.17677669529663687f + rel_tab[ridx * 16 + head] + mask;
        sarr[c] = sv;
        mx = fmaxf(mx, sv);
      }
      float sum = 0.f;
#pragma unroll
      for (int c = 0; c < 49; ++c) { float e = __expf(sarr[c] - mx); sarr[c] = e; sum += e; }
      float inv = 1.f / sum;
      float o[32];
#pragma unroll
      for (int d = 0; d < 32; ++d) o[d] = 0.f;
#pragma unroll
      for (int c = 0; c < 49; ++c) {
        float p = sarr[c];
#pragma unroll
        for (int d = 0; d < 32; ++d) o[d] += p * ldsV[wave][c * 32 + d];
      }
      unsigned short* dst = qkv + base + (size_t)r * 1536 + head * 32;  // in place
#pragma unroll
      for (int d8 = 0; d8 < 4; ++d8) {
        short8 pk;
#pragma unroll
        for (int k = 0; k < 8; ++k) pk[k] = (short)f2bf(o[d8 * 8 + k] * inv);
        *(short8*)(dst + d8 * 8) = pk;
      }
    }
  }
}

// -------------------------------------------------------------------------
extern "C" void kernel_launch(void* const* d_in, const int* in_sizes, int n_in,
                              void* d_out, int out_size, void* d_ws, size_t ws_size,
                              hipStream_t stream) {
  const float* x1     = (const float*)d_in[0];
  // d_in[1] = x2 : dead code in reference (xw[:,:,:C] uses only the x1 branch)
  const float* n1g    = (const float*)d_in[2];
  const float* n1b    = (const float*)d_in[3];
  const float* qkv_w  = (const float*)d_in[4];
  const float* qkv_b  = (const float*)d_in[5];
  const float* rel_t  = (const float*)d_in[6];
  const float* proj_w = (const float*)d_in[7];
  const float* proj_b = (const float*)d_in[8];
  const float* n2g    = (const float*)d_in[9];
  const float* n2b    = (const float*)d_in[10];
  const float* fc1_w  = (const float*)d_in[11];
  const float* fc1_b  = (const float*)d_in[12];
  const float* fc2_w  = (const float*)d_in[13];
  const float* fc2_b  = (const float*)d_in[14];
  float* outp = (float*)d_out;   // fp32; also holds x (residual-1 result)

  // ws layout (= 205,922,304 B, same as the passing round-4 footprint):
  //   stats 401,408 | a1w 51,380,224 (bf16) | bufQ 154,140,672 (bf16)
  //   phase B: h = a1w..bufQ contiguous (50176 x 2048 bf16 = 205,520,896)
  const size_t statB = (size_t)TOKENS * sizeof(float2);
  char* ws = (char*)d_ws;
  float2* stats = (float2*)ws;
  unsigned short* a1w  = (unsigned short*)(ws + statB);
  unsigned short* bufQ = a1w + (size_t)TOKENS * 512;
  unsigned short* hbuf = a1w;

  // 1. LN1 + roll + partition -> a1w (bf16, windowed order)
  prep_ln1<<<TOKENS / 4, 256, 0, stream>>>(x1, n1g, n1b, a1w);
  // 2. QKV: 50176x1536x512, block col-loops all 12 tiles
  gemm_col<0, 0><<<dim3(392, 1), 256, 0, stream>>>(
      a1w, qkv_w, qkv_b, bufQ, nullptr, nullptr, nullptr, nullptr, 1536, 512, 512, 12);
  // 3. attention (O in place into Q columns)
  attn_kernel<<<1024, 256, 0, stream>>>(bufQ, rel_t);
  // 4. proj: A = O (stride 1536), scatter + x1 residual -> d_out fp32
  gemm_col<0, 1><<<dim3(392, 1), 256, 0, stream>>>(
      bufQ, proj_w, proj_b, outp, x1, nullptr, nullptr, nullptr, 512, 512, 1536, 4);
  // 5. LN2 stats over x (= d_out)
  ln_stats_kernel<<<TOKENS / 4, 256, 0, stream>>>(outp, stats);
  // 6. fc1 (fused LN2 + GELU): 50176x2048x512, CB=4 x NY=4
  gemm_col<2, 2><<<dim3(392, 4), 256, 0, stream>>>(
      outp, fc1_w, fc1_b, hbuf, nullptr, stats, n2g, n2b, 2048, 512, 512, 4);
  // 7. fc2 (+x residual, in place): 50176x512x2048
  gemm_col<0, 3><<<dim3(392, 1), 256, 0, stream>>>(
      hbuf, fc2_w, fc2_b, outp, outp, nullptr, nullptr, nullptr, 512, 2048, 2048, 4);
}